// Round 5
// baseline (264.637 us; speedup 1.0000x reference)
//
#include <hip/hip_runtime.h>
#include <hip/hip_fp16.h>

#define N_NODES 50000
#define N_EDGES 600000

typedef _Float16 f16;
typedef f16 f16x8 __attribute__((ext_vector_type(8)));
typedef float f32x4 __attribute__((ext_vector_type(4)));
typedef unsigned int u32;
typedef u32 u32x4 __attribute__((ext_vector_type(4)));

// ---------------- CSR build ----------------

__global__ __launch_bounds__(256) void init_deg_cnt(float* deg, int* cnt, int n) {
    int i = blockIdx.x * blockDim.x + threadIdx.x;
    if (i < n) { deg[i] = 1.0f; cnt[i] = 0; }   // deg: +1 from added self-loop
}

__global__ __launch_bounds__(256) void hist_edges(const int* __restrict__ ei,
                                                  const float* __restrict__ ew,
                                                  float* __restrict__ deg,
                                                  int* __restrict__ cnt, int E) {
    int e = blockIdx.x * blockDim.x + threadIdx.x;
    if (e < E) {
        int r = ei[e], c = ei[E + e];
        if (r != c) {
            atomicAdd(&deg[c], ew[e]);
            atomicAdd(&cnt[c], 1);
        }
    }
}

__global__ __launch_bounds__(256) void finalize_dis(float* deg, int n) {
    int i = blockIdx.x * blockDim.x + threadIdx.x;
    if (i < n) deg[i] = rsqrtf(deg[i]);   // deg >= 1
}

// exclusive scan of cnt -> start (3 passes)
__global__ __launch_bounds__(256) void scan1(const int* __restrict__ cnt,
                                             int* __restrict__ start,
                                             int* __restrict__ bsum, int n) {
    __shared__ int s[256];
    int t = threadIdx.x, i = blockIdx.x * 256 + t;
    int v = (i < n) ? cnt[i] : 0;
    s[t] = v;
    __syncthreads();
    for (int off = 1; off < 256; off <<= 1) {
        int add = (t >= off) ? s[t - off] : 0;
        __syncthreads();
        s[t] += add;
        __syncthreads();
    }
    if (i < n) start[i] = s[t] - v;
    if (t == 255) bsum[blockIdx.x] = s[255];
}

__global__ __launch_bounds__(256) void scan2(int* __restrict__ bsum,
                                             int* __restrict__ start, int nb, int n) {
    __shared__ int s[256];
    int t = threadIdx.x;
    int v = (t < nb) ? bsum[t] : 0;
    s[t] = v;
    __syncthreads();
    for (int off = 1; off < 256; off <<= 1) {
        int add = (t >= off) ? s[t - off] : 0;
        __syncthreads();
        s[t] += add;
        __syncthreads();
    }
    if (t < nb) bsum[t] = s[t] - v;
    if (t == nb - 1) start[n] = s[t];
}

__global__ __launch_bounds__(256) void scan3(int* __restrict__ start,
                                             const int* __restrict__ bsum, int n) {
    int i = blockIdx.x * blockDim.x + threadIdx.x;
    if (i < n) start[i] += bsum[i >> 8];
}

// fill sorted edges; bumps start[c]: afterwards start[c] = END of node c's range.
__global__ __launch_bounds__(256) void fill_edges(const int* __restrict__ ei,
                                                  const float* __restrict__ ew,
                                                  const float* __restrict__ dis,
                                                  int* __restrict__ start,
                                                  u32* __restrict__ sed, int E) {
    int e = blockIdx.x * blockDim.x + threadIdx.x;
    if (e >= E) return;
    int r = ei[e], c = ei[E + e];
    if (r == c) return;                      // self-loops dropped (w_eff = 0)
    float v = dis[r] * ew[e] * dis[c];
    u32 hb = __half_as_ushort(__float2half(v));
    int pos = atomicAdd(&start[c], 1);
    sed[pos] = (hb << 16) | (u32)r;          // row in low 16 bits (N < 65536)
}

// ---------------- weight prep: f16, layer-2 concat ----------------

__global__ __launch_bounds__(256) void conv_weights(const float* __restrict__ W1,
                                                    const float* __restrict__ Wmu,
                                                    const float* __restrict__ Wls,
                                                    f16* __restrict__ Wc1,
                                                    f16* __restrict__ Wc2) {
    int i = blockIdx.x * 256 + threadIdx.x;   // 0..16383
    Wc1[i] = (f16)W1[i];
    Wc2[i] = (f16)((i < 8192) ? Wmu[i] : Wls[i - 8192]);
}

// ---------------- MFMA f16 GEMM: C = A[M][128] @ Wc[128][128]^T ----------------
// A (when f16) and C live in QUARTERED layout: [4][M][32] f16 (quarter q = ch/32).
// 64x128 tile/block, whole K=128 in LDS, XOR-swizzled 16B chunks.

template<bool A_F16>
__global__ __launch_bounds__(256) void gemm_mfma(const void* __restrict__ Aptr,
                                                 const f16* __restrict__ Wc,
                                                 f16* __restrict__ Cbase, int M) {
    __shared__ f16 sA[64 * 128];
    __shared__ f16 sW[128 * 128];
    const int tid = threadIdx.x;
    const int row0 = blockIdx.x * 64;

    // stage W: 2048 16B chunks, 8/thread, swizzled by row&15
    {
        const u32x4* src = (const u32x4*)Wc;
        u32x4* dst = (u32x4*)sW;
        #pragma unroll
        for (int i = 0; i < 8; ++i) {
            int c = tid + i * 256;
            int r = c >> 4, ch = c & 15;
            dst[r * 16 + (ch ^ (r & 15))] = src[c];
        }
    }
    // stage A: 1024 16B f16-chunks, 4/thread
    if (A_F16) {
        const u32x4* src = (const u32x4*)Aptr;   // quartered: [4][M][4] u32x4
        u32x4* dst = (u32x4*)sA;
        #pragma unroll
        for (int i = 0; i < 4; ++i) {
            int c = tid + i * 256;
            int r = c >> 4, ch = c & 15;
            int gr = row0 + r;
            u32x4 v = {};
            if (gr < M) v = src[(size_t)(ch >> 2) * M * 4 + gr * 4 + (ch & 3)];
            dst[r * 16 + (ch ^ (r & 15))] = v;
        }
    } else {
        const float4* src = (const float4*)Aptr;   // fp32 x, row-major [M][128]
        u32x4* dst = (u32x4*)sA;
        #pragma unroll
        for (int i = 0; i < 4; ++i) {
            int c = tid + i * 256;
            int r = c >> 4, ch = c & 15;
            int gr = row0 + r;
            f16x8 h = {};
            if (gr < M) {
                float4 a = src[gr * 32 + ch * 2];
                float4 b = src[gr * 32 + ch * 2 + 1];
                h[0] = (f16)a.x; h[1] = (f16)a.y; h[2] = (f16)a.z; h[3] = (f16)a.w;
                h[4] = (f16)b.x; h[5] = (f16)b.y; h[6] = (f16)b.z; h[7] = (f16)b.w;
            }
            dst[r * 16 + (ch ^ (r & 15))] = *(const u32x4*)&h;
        }
    }
    __syncthreads();

    const int wave = tid >> 6, lane = tid & 63;
    const int m = lane & 15, kq = lane >> 4;
    const int wcol0 = wave * 32;

    f32x4 acc[4][2] = {};
    const f16x8* sa = (const f16x8*)sA;
    const f16x8* sw = (const f16x8*)sW;

    #pragma unroll
    for (int ks = 0; ks < 4; ++ks) {
        int cidx = ks * 4 + kq;
        f16x8 bfrag[2];
        #pragma unroll
        for (int cf = 0; cf < 2; ++cf) {
            int wr = wcol0 + cf * 16 + m;          // W row = output col
            bfrag[cf] = sw[wr * 16 + (cidx ^ m)];
        }
        #pragma unroll
        for (int rf = 0; rf < 4; ++rf) {
            int ar = rf * 16 + m;
            f16x8 afrag = sa[ar * 16 + (cidx ^ m)];
            #pragma unroll
            for (int cf = 0; cf < 2; ++cf)
                acc[rf][cf] = __builtin_amdgcn_mfma_f32_16x16x32_f16(
                    afrag, bfrag[cf], acc[rf][cf], 0, 0, 0);
        }
    }

    __syncthreads();                 // done reading sA; reuse as output tile
    #pragma unroll
    for (int rf = 0; rf < 4; ++rf)
        #pragma unroll
        for (int cf = 0; cf < 2; ++cf)
            #pragma unroll
            for (int r = 0; r < 4; ++r)
                sA[(rf * 16 + kq * 4 + r) * 128 + wcol0 + cf * 16 + m] =
                    (f16)acc[rf][cf][r];
    __syncthreads();
    {
        const u32x4* src = (const u32x4*)sA;
        u32x4* dst = (u32x4*)Cbase;   // quartered
        #pragma unroll
        for (int i = 0; i < 4; ++i) {
            int c = tid + i * 256;
            int r = c >> 4, ch = c & 15;
            int gr = row0 + r;
            if (gr < M)
                dst[(size_t)(ch >> 2) * M * 4 + gr * 4 + (ch & 3)] = src[c];
        }
    }
}

// ---------------- CSR gather, quarter-split, shfl-staged edges ----------------
// quarter q = blockIdx&3 -> under round-robin block->XCD each XCD touches ONE
// 3.2MB quarter (fits 4MB L2). Wave = one (node, q); lanes 0-31 process even
// edges, 32-63 odd edges, each lane owns channel (lane&31); fold at the end.

#define NM(d) __half2float(__ushort_as_half((unsigned short)((d) >> 16)))

__device__ __forceinline__ float gather_core(const u32* __restrict__ sed,
                                             const f16* __restrict__ src,
                                             int beg, int end, int ch, int eoff) {
    float acc = 0.f;
    int p = beg;
    while (p < end) {
        int nstage = end - p;
        if (nstage > 64) nstage = 64;
        int lane = threadIdx.x & 63;
        u32 se = (lane < nstage) ? sed[p + lane] : 0u;
        int i = 0;
        for (; i + 8 <= nstage; i += 8) {
            u32 d0 = __shfl(se, i + eoff);
            u32 d1 = __shfl(se, i + 2 + eoff);
            u32 d2 = __shfl(se, i + 4 + eoff);
            u32 d3 = __shfl(se, i + 6 + eoff);
            float v0 = (float)src[(d0 & 0xFFFFu) * 32 + ch];
            float v1 = (float)src[(d1 & 0xFFFFu) * 32 + ch];
            float v2 = (float)src[(d2 & 0xFFFFu) * 32 + ch];
            float v3 = (float)src[(d3 & 0xFFFFu) * 32 + ch];
            acc += NM(d0) * v0 + NM(d1) * v1 + NM(d2) * v2 + NM(d3) * v3;
        }
        for (; i < nstage; i += 2) {
            int e = i + eoff;
            if (e < nstage) {
                u32 d = __shfl(se, e);
                acc += NM(d) * (float)src[(d & 0xFFFFu) * 32 + ch];
            }
        }
        p += nstage;
    }
    return acc;
}

__global__ __launch_bounds__(256) void gather_relu(const u32* __restrict__ sed,
                                                   const int* __restrict__ start,
                                                   const float* __restrict__ dis,
                                                   const f16* __restrict__ xw,   // [4][n][32]
                                                   const float* __restrict__ b,
                                                   f16* __restrict__ h, int n) { // [4][n][32]
    int bid = blockIdx.x;
    int q = bid & 3;
    int wid = (bid >> 2) * 4 + (threadIdx.x >> 6);
    int lane = threadIdx.x & 63;
    if (wid >= n) return;
    const f16* src = xw + (size_t)q * n * 32;
    int beg = (wid == 0) ? 0 : start[wid - 1];
    int end = start[wid];
    int ch = lane & 31, eoff = lane >> 5;
    float acc = gather_core(sed, src, beg, end, ch, eoff);
    acc += __shfl_xor(acc, 32);
    float di = dis[wid];
    float inv = di * di;   // 1/deg
    float xv = (float)src[wid * 32 + ch];
    float o = fmaxf(acc + xv * inv + b[q * 32 + ch], 0.f);
    if (lane < 32) h[(size_t)q * n * 32 + wid * 32 + ch] = (f16)o;
}

__global__ __launch_bounds__(256) void gather_out(const u32* __restrict__ sed,
                                                  const int* __restrict__ start,
                                                  const float* __restrict__ dis,
                                                  const f16* __restrict__ hw,   // [4][n][32]
                                                  const float* __restrict__ bmu,
                                                  const float* __restrict__ bls,
                                                  float* __restrict__ out, int n) {
    int bid = blockIdx.x;
    int q = bid & 3;
    int wid = (bid >> 2) * 4 + (threadIdx.x >> 6);
    int lane = threadIdx.x & 63;
    if (wid >= n) return;
    const f16* src = hw + (size_t)q * n * 32;
    int beg = (wid == 0) ? 0 : start[wid - 1];
    int end = start[wid];
    int ch = lane & 31, eoff = lane >> 5;
    float acc = gather_core(sed, src, beg, end, ch, eoff);
    acc += __shfl_xor(acc, 32);
    float di = dis[wid];
    float inv = di * di;
    float xv = (float)src[wid * 32 + ch];
    float bb = (q < 2) ? bmu[(q & 1) * 32 + ch] : bls[(q & 1) * 32 + ch];
    float o = acc + xv * inv + bb;
    // quarters 0,1 -> mu cols 0..63 ; quarters 2,3 -> logstd cols 0..63
    if (lane < 32)
        out[(size_t)(q >> 1) * n * 64 + (size_t)wid * 64 + (q & 1) * 32 + ch] = o;
}

extern "C" void kernel_launch(void* const* d_in, const int* in_sizes, int n_in,
                              void* d_out, int out_size, void* d_ws, size_t ws_size,
                              hipStream_t stream) {
    const float* x   = (const float*)d_in[0];
    const int*   ei  = (const int*)d_in[1];
    const float* ew  = (const float*)d_in[2];
    const float* W1  = (const float*)d_in[3];
    const float* b1  = (const float*)d_in[4];
    const float* Wmu = (const float*)d_in[5];
    const float* bmu = (const float*)d_in[6];
    const float* Wls = (const float*)d_in[7];
    const float* bls = (const float*)d_in[8];
    float* out = (float*)d_out;

    // workspace layout (u32 units; all bases 16B-aligned)
    float* dis   = (float*)d_ws;                    // 50000
    int*   start = (int*)d_ws + 50000;              // 50001 (+pad)
    int*   cnt   = (int*)d_ws + 100004;             // 50000
    int*   bsum  = (int*)d_ws + 150004;             // 256
    u32*   sed   = (u32*)d_ws + 150260;             // 600000
    f16*   Wc1   = (f16*)((u32*)d_ws + 750260);     // 16384 f16
    f16*   Wc2   = (f16*)((u32*)d_ws + 758452);     // 16384 f16
    f16*   Abuf  = (f16*)((u32*)d_ws + 766644);     // [4][N][32] f16 (xw -> hw)
    f16*   Hbuf  = (f16*)((u32*)d_ws + 3966644);    // [4][N][32] f16 (h)

    const int N = N_NODES, E = N_EDGES;
    const int NB = (N + 255) / 256;   // 196
    const int GB = 4 * ((N + 3) / 4); // gather blocks: (node-group, quarter)

    // CSR build
    init_deg_cnt<<<NB, 256, 0, stream>>>(dis, cnt, N);
    hist_edges<<<(E + 255) / 256, 256, 0, stream>>>(ei, ew, dis, cnt, E);
    finalize_dis<<<NB, 256, 0, stream>>>(dis, N);
    scan1<<<NB, 256, 0, stream>>>(cnt, start, bsum, N);
    scan2<<<1, 256, 0, stream>>>(bsum, start, NB, N);
    scan3<<<NB, 256, 0, stream>>>(start, bsum, N);
    fill_edges<<<(E + 255) / 256, 256, 0, stream>>>(ei, ew, dis, start, sed, E);

    conv_weights<<<64, 256, 0, stream>>>(W1, Wmu, Wls, Wc1, Wc2);

    // layer 1
    gemm_mfma<false><<<(N + 63) / 64, 256, 0, stream>>>(x, Wc1, Abuf, N);
    gather_relu<<<GB, 256, 0, stream>>>(sed, start, dis, Abuf, b1, Hbuf, N);

    // layer 2 (mu‖logstd in one GEMM)
    gemm_mfma<true><<<(N + 63) / 64, 256, 0, stream>>>(Hbuf, Wc2, Abuf, N);
    gather_out<<<GB, 256, 0, stream>>>(sed, start, dis, Abuf, bmu, bls, out, N);
}